// Round 10
// baseline (53.973 us; speedup 1.0000x reference)
//
#include <hip/hip_runtime.h>
#include <hip/hip_bf16.h>

typedef __attribute__((ext_vector_type(8))) short s8x8;
typedef __attribute__((ext_vector_type(4))) float f32x4;

union FragU { s8x8 v; unsigned d[4]; };

__device__ __forceinline__ ushort f2bf(float x) {   // RTNE single rounding
    union { float f; unsigned u; } c; c.f = x;
    unsigned r = c.u + 0x7FFFu + ((c.u >> 16) & 1u);
    return (ushort)(r >> 16);
}
__device__ __forceinline__ float bf2f(ushort b) {
    union { unsigned u; float f; } c; c.u = ((unsigned)b) << 16;
    return c.f;
}
__device__ __forceinline__ unsigned cvt_pk(float lo, float hi) {
    unsigned r;
    asm("v_cvt_pk_bf16_f32 %0, %1, %2" : "=v"(r) : "v"(lo), "v"(hi));
    return r;
}
__device__ __forceinline__ float asf(unsigned u) {
    union { unsigned u; float f; } c; c.u = u; return c.f;
}

// ---------------------------------------------------------------------------
// Kernel 1: proj GEMM Y = X*W^T + b (z: 0=q,1=k,2=v). VERIFIED (R8/R9).
// One wave per block, tile 16 rows x 64 cols; grid (96,4,3).
// ---------------------------------------------------------------------------
__global__ __launch_bounds__(64) void proj_kernel(
    const float* __restrict__ Xq, const float* __restrict__ Xk,
    const float* __restrict__ Xv,
    const float* __restrict__ Wq, const float* __restrict__ bq,
    const float* __restrict__ Wk, const float* __restrict__ bk,
    const float* __restrict__ Wv, const float* __restrict__ bv,
    ushort* __restrict__ qh, ushort* __restrict__ ql,
    ushort* __restrict__ kh, ushort* __restrict__ kl,
    ushort* __restrict__ vh, float* __restrict__ part)
{
    const int z = blockIdx.z;
    const float* X    = (z == 0) ? Xq : (z == 1) ? Xk : Xv;
    const float* W    = (z == 0) ? Wq : (z == 1) ? Wk : Wv;
    const float* bias = (z == 0) ? bq : (z == 1) ? bk : bv;

    const int lane = threadIdx.x;
    const int lg   = lane >> 4;
    const int ll   = lane & 15;
    const int bx   = blockIdx.x;
    const int row0 = bx * 16;
    const int col0 = blockIdx.y * 64;

    f32x4 acc[4];
    #pragma unroll
    for (int ct = 0; ct < 4; ++ct) acc[ct] = (f32x4){0.f, 0.f, 0.f, 0.f};

    for (int kk = 0; kk < 8; ++kk) {
        FragU ah, al;
        {
            const float* xp = &X[(size_t)(row0 + ll) * 256 + kk * 32 + lg * 8];
            const float4 x0 = *(const float4*)&xp[0];
            const float4 x1 = *(const float4*)&xp[4];
            const float xv[8] = {x0.x, x0.y, x0.z, x0.w, x1.x, x1.y, x1.z, x1.w};
            #pragma unroll
            for (int i = 0; i < 4; ++i) {
                const unsigned hd = cvt_pk(xv[2 * i], xv[2 * i + 1]);
                ah.d[i] = hd;
                al.d[i] = cvt_pk(xv[2 * i]     - asf(hd << 16),
                                 xv[2 * i + 1] - asf(hd & 0xffff0000u));
            }
        }
        #pragma unroll
        for (int ct = 0; ct < 4; ++ct) {
            const float* wp = &W[(size_t)(col0 + ct * 16 + ll) * 256 + kk * 32 + lg * 8];
            const float4 w0 = *(const float4*)&wp[0];
            const float4 w1 = *(const float4*)&wp[4];
            const float wv[8] = {w0.x, w0.y, w0.z, w0.w, w1.x, w1.y, w1.z, w1.w};
            FragU bh, bl;
            #pragma unroll
            for (int i = 0; i < 4; ++i) {
                const unsigned hd = cvt_pk(wv[2 * i], wv[2 * i + 1]);
                bh.d[i] = hd;
                bl.d[i] = cvt_pk(wv[2 * i]     - asf(hd << 16),
                                 wv[2 * i + 1] - asf(hd & 0xffff0000u));
            }
            acc[ct] = __builtin_amdgcn_mfma_f32_16x16x32_bf16(ah.v, bh.v, acc[ct], 0, 0, 0);
            acc[ct] = __builtin_amdgcn_mfma_f32_16x16x32_bf16(al.v, bh.v, acc[ct], 0, 0, 0);
            acc[ct] = __builtin_amdgcn_mfma_f32_16x16x32_bf16(ah.v, bl.v, acc[ct], 0, 0, 0);
        }
    }

    const int ae  = bx / 24;                     // a (q) or e (k,v)
    const int rbl = bx - ae * 24;
    float bct[4];
    #pragma unroll
    for (int ct = 0; ct < 4; ++ct) bct[ct] = bias[col0 + ct * 16 + ll];

    if (z != 2) {
        #pragma unroll
        for (int ct = 0; ct < 4; ++ct) {
            const int d = col0 + ct * 16 + ll;
            const int hd = d >> 5;
            const int c = d & 31;
            #pragma unroll
            for (int j = 0; j < 4; ++j) {
                const int n = rbl * 16 + lg * 4 + j;
                const float v = acc[ct][j] + bct[ct];
                const ushort hb = f2bf(v);
                const ushort lb = f2bf(v - bf2f(hb));
                if (z == 0) {
                    const size_t idx = ((size_t)((ae * 8 + hd) * 384 + n)) * 32 + c;
                    qh[idx] = hb; ql[idx] = lb;
                } else {
                    const size_t idx =
                        ((size_t)(((ae * 8 + hd) * 4 + (c >> 3)) * 384 + n)) * 8 + (c & 7);
                    kh[idx] = hb; kl[idx] = lb;
                }
            }
        }
        // exact fp32 column sums over this block's 16 rows (incl. bias)
        #pragma unroll
        for (int ct = 0; ct < 4; ++ct) {
            float cs = 4.f * bct[ct];
            #pragma unroll
            for (int j = 0; j < 4; ++j) cs += acc[ct][j];
            cs += __shfl_xor(cs, 16);
            cs += __shfl_xor(cs, 32);
            if (lg == 0)
                part[((size_t)(z * 4 + ae) * 24 + rbl) * 256 + col0 + ct * 16 + ll] = cs;
        }
    } else {
        #pragma unroll
        for (int ct = 0; ct < 4; ++ct) {
            const int d = col0 + ct * 16 + ll;
            const int hd = d >> 5;
            const int c = d & 31;
            ushort p[4];
            #pragma unroll
            for (int j = 0; j < 4; ++j) p[j] = f2bf(acc[ct][j] + bct[ct]);
            const int m0 = rbl * 16 + lg * 4;
            const size_t basei = ((size_t)((ae * 8 + hd) * 32 + c)) * 384 + m0;
            *(uint2*)&vh[basei] =
                make_uint2((unsigned)p[0] | ((unsigned)p[1] << 16),
                           (unsigned)p[2] | ((unsigned)p[3] << 16));
        }
    }
}

// ---------------------------------------------------------------------------
// Kernel 2: stats. VERIFIED (R9). 1 block x 256 threads -> w[16].
// ---------------------------------------------------------------------------
__global__ __launch_bounds__(256) void stats_kernel(
    const float* __restrict__ part, float* __restrict__ wout)
{
    __shared__ float ws4[4][16];
    __shared__ float cellsh[16];
    const int tid = threadIdx.x;
    const int lane = tid & 63;
    const int wv = tid >> 6;

    float qs[4], ks[4];
    #pragma unroll
    for (int a2 = 0; a2 < 4; ++a2) {
        const float* pq = &part[(size_t)(0 * 4 + a2) * 24 * 256 + tid];
        const float* pk = &part[(size_t)(1 * 4 + a2) * 24 * 256 + tid];
        float sq = 0.f, sk = 0.f;
        #pragma unroll
        for (int r = 0; r < 24; ++r) {
            sq += pq[r * 256];
            sk += pk[r * 256];
        }
        qs[a2] = sq; ks[a2] = sk;
    }
    #pragma unroll
    for (int i = 0; i < 16; ++i) {
        float v = qs[i >> 2] * ks[i & 3];
        v += __shfl_xor(v, 1);
        v += __shfl_xor(v, 2);
        v += __shfl_xor(v, 4);
        v += __shfl_xor(v, 8);
        v += __shfl_xor(v, 16);
        v += __shfl_xor(v, 32);
        if (lane == 0) ws4[wv][i] = v;
    }
    __syncthreads();
    if (tid < 16)
        cellsh[tid] = 0.17677669529663687f *
            (ws4[0][tid] + ws4[1][tid] + ws4[2][tid] + ws4[3][tid]);
    __syncthreads();
    if (tid == 0) {
        const int TR[12][4] = {
            {0,1,2,3},{0,2,3,1},{0,3,1,2},{1,2,0,3},{1,0,3,2},{1,3,2,0},
            {2,3,0,1},{2,0,1,3},{2,1,3,0},{3,1,0,2},{3,0,2,1},{3,2,1,0}};
        const float denom = 4.0f * 8.0f * 384.0f * 384.0f;
        float pos[12];
        float psum = 0.f;
        for (int r = 0; r < 12; ++r) {
            float s = 0.f;
            for (int a2 = 0; a2 < 4; ++a2) s += cellsh[a2 * 4 + TR[r][a2]];
            const float pooled = s / denom;
            pos[r] = pooled * pooled;
            psum += pos[r];
        }
        float w[16];
        for (int i = 0; i < 16; ++i) w[i] = 0.f;
        const float ip = 1.f / psum;
        for (int r = 0; r < 12; ++r)
            for (int a2 = 0; a2 < 4; ++a2) w[a2 * 4 + TR[r][a2]] += pos[r] * ip;
        for (int i = 0; i < 16; ++i) wout[i] = w[i];
    }
}

// ---------------------------------------------------------------------------
// Kernel 3: fused attention + combine. One block per (a,h) x n-strip(48);
// grid (8, 32), block 192 (3 waves, each one 16-row tile). Loops e=0..3
// reusing the same LDS staging; merges each e's normalized result with
// weight w[a,e] into the output accumulator; writes out directly.
// Inner loop math identical to the VERIFIED R9 attention (3-term QK^T,
// f2bf P, single-term bf16 PV).
// ---------------------------------------------------------------------------
__global__ __launch_bounds__(192) void attn_fused_kernel(
    const ushort* __restrict__ qhb, const ushort* __restrict__ qlb,
    const ushort* __restrict__ khb, const ushort* __restrict__ klb,
    const ushort* __restrict__ vhb, const float* __restrict__ wbuf,
    float* __restrict__ out)
{
    __shared__ ushort Kh[4 * 1544];      // [kblk][m:192][8] + 8-pad per kblk
    __shared__ ushort Kl[4 * 1544];
    __shared__ ushort Vh[32 * 200];      // [c][m:192] + pad
    __shared__ ushort Pl[48 * 40];       // [wave*16 + row][m:32 + pad]

    const int strip = blockIdx.x;          // 0..7, 48 rows each
    const int ah    = blockIdx.y;          // a*8 + h
    const int hh    = ah & 7;
    const int aa    = ah >> 3;
    const int tid   = threadIdx.x;
    const int wave  = tid >> 6;
    const int lane  = tid & 63;
    const int lg    = lane >> 4;
    const int ll    = lane & 15;

    const int n0 = strip * 48 + wave * 16;
    s8x8 qfh, qfl;
    {
        const size_t off = (size_t)(ah * 384 + n0 + ll) * 32 + lg * 8;
        qfh = *(const s8x8*)&qhb[off];
        qfl = *(const s8x8*)&qlb[off];
    }

    f32x4 oout[2];
    oout[0] = (f32x4){0.f, 0.f, 0.f, 0.f};
    oout[1] = (f32x4){0.f, 0.f, 0.f, 0.f};
    const float sc = 0.17677669529663687f; // 1/sqrt(32)

    for (int e = 0; e < 4; ++e) {
        const int e8h = e * 8 + hh;
        f32x4 oacc[2];
        oacc[0] = (f32x4){0.f, 0.f, 0.f, 0.f};
        oacc[1] = (f32x4){0.f, 0.f, 0.f, 0.f};
        float lsum[4] = {0.f, 0.f, 0.f, 0.f};

        for (int half = 0; half < 2; ++half) {
            #pragma unroll
            for (int i = 0; i < 4; ++i) {
                const size_t src = ((size_t)(e8h * 4 + i) * 384 + half * 192 + tid) * 8;
                *(uint4*)&Kh[i * 1544 + tid * 8] = *(const uint4*)&khb[src];
                *(uint4*)&Kl[i * 1544 + tid * 8] = *(const uint4*)&klb[src];
            }
            #pragma unroll
            for (int i = 0; i < 4; ++i) {
                const int u = tid + 192 * i;
                const int c = u / 24;
                const int m8 = (u - c * 24) * 8;
                *(uint4*)&Vh[c * 200 + m8] =
                    *(const uint4*)&vhb[(size_t)(e8h * 32 + c) * 384 + half * 192 + m8];
            }
            __syncthreads();

            for (int mt2 = 0; mt2 < 6; ++mt2) {
                #pragma unroll
                for (int sub = 0; sub < 2; ++sub) {
                    const int mt = mt2 * 2 + sub;
                    const s8x8 kfh = *(const s8x8*)&Kh[lg * 1544 + (mt * 16 + ll) * 8];
                    const s8x8 kfl = *(const s8x8*)&Kl[lg * 1544 + (mt * 16 + ll) * 8];
                    f32x4 s = {0.f, 0.f, 0.f, 0.f};
                    __builtin_amdgcn_s_setprio(1);
                    s = __builtin_amdgcn_mfma_f32_16x16x32_bf16(qfh, kfh, s, 0, 0, 0);
                    s = __builtin_amdgcn_mfma_f32_16x16x32_bf16(qfl, kfh, s, 0, 0, 0);
                    s = __builtin_amdgcn_mfma_f32_16x16x32_bf16(qfh, kfl, s, 0, 0, 0);
                    __builtin_amdgcn_s_setprio(0);
                    #pragma unroll
                    for (int j = 0; j < 4; ++j) {
                        const float p = __expf(s[j] * sc);
                        lsum[j] += p;
                        Pl[(wave * 16 + lg * 4 + j) * 40 + sub * 16 + ll] = f2bf(p);
                    }
                }
                const int mloc = mt2 * 32;
                const s8x8 vf0 = *(const s8x8*)&Vh[(0  + ll) * 200 + mloc + lg * 8];
                const s8x8 vf1 = *(const s8x8*)&Vh[(16 + ll) * 200 + mloc + lg * 8];
                const s8x8 pa = *(const s8x8*)&Pl[(wave * 16 + ll) * 40 + lg * 8];
                __builtin_amdgcn_s_setprio(1);
                oacc[0] = __builtin_amdgcn_mfma_f32_16x16x32_bf16(pa, vf0, oacc[0], 0, 0, 0);
                oacc[1] = __builtin_amdgcn_mfma_f32_16x16x32_bf16(pa, vf1, oacc[1], 0, 0, 0);
                __builtin_amdgcn_s_setprio(0);
            }
            __syncthreads();
        }

        // merge this e into the output accumulator (registers only)
        const float we = wbuf[aa * 4 + e];
        #pragma unroll
        for (int j = 0; j < 4; ++j) {
            float L = lsum[j];
            L += __shfl_xor(L, 1);
            L += __shfl_xor(L, 2);
            L += __shfl_xor(L, 4);
            L += __shfl_xor(L, 8);
            const float f = we / L;
            oout[0][j] += f * oacc[0][j];
            oout[1][j] += f * oacc[1][j];
        }
    }

    // write out[a][n][h*32+c]
    #pragma unroll
    for (int j = 0; j < 4; ++j) {
        const int row = n0 + lg * 4 + j;
        const size_t base = ((size_t)(aa * 384 + row)) * 256 + hh * 32;
        out[base + 0  + ll] = oout[0][j];
        out[base + 16 + ll] = oout[1][j];
    }
}

// ---------------------------------------------------------------------------
extern "C" void kernel_launch(void* const* d_in, const int* in_sizes, int n_in,
                              void* d_out, int out_size, void* d_ws, size_t ws_size,
                              hipStream_t stream)
{
    const float* in_q = (const float*)d_in[0];
    const float* in_k = (const float*)d_in[1];
    const float* in_v = (const float*)d_in[2];
    const float* Wq   = (const float*)d_in[3];
    const float* bq   = (const float*)d_in[4];
    const float* Wk   = (const float*)d_in[5];
    const float* bk   = (const float*)d_in[6];
    const float* Wv   = (const float*)d_in[7];
    const float* bv   = (const float*)d_in[8];

    ushort* qh = (ushort*)d_ws;               // 393216
    ushort* ql = qh + 393216;                 // 393216
    ushort* kh = ql + 393216;                 // 393216
    ushort* kl = kh + 393216;                 // 393216
    ushort* vh = kl + 393216;                 // 393216
    float*  pt = (float*)(vh + 393216);       // 49152 floats (column sums)
    float*  wb = pt + 49152;                  // 16 weights
    float*  outp = (float*)d_out;

    dim3 pgrid(96, 4, 3);
    proj_kernel<<<pgrid, 64, 0, stream>>>(in_q, in_k, in_v, Wq, bq, Wk, bk,
                                          Wv, bv, qh, ql, kh, kl, vh, pt);
    stats_kernel<<<1, 256, 0, stream>>>(pt, wb);
    dim3 agrid(8, 32);
    attn_fused_kernel<<<agrid, 192, 0, stream>>>(qh, ql, kh, kl, vh, wb, outp);
}

// Round 11
// 46.007 us; speedup vs baseline: 1.1732x; 1.1732x over previous
//
#include <hip/hip_runtime.h>
#include <hip/hip_bf16.h>

typedef __attribute__((ext_vector_type(8))) short s8x8;
typedef __attribute__((ext_vector_type(4))) float f32x4;

union FragU { s8x8 v; unsigned d[4]; };

__device__ __forceinline__ ushort f2bf(float x) {   // RTNE single rounding
    union { float f; unsigned u; } c; c.f = x;
    unsigned r = c.u + 0x7FFFu + ((c.u >> 16) & 1u);
    return (ushort)(r >> 16);
}
__device__ __forceinline__ float bf2f(ushort b) {
    union { unsigned u; float f; } c; c.u = ((unsigned)b) << 16;
    return c.f;
}
__device__ __forceinline__ unsigned cvt_pk(float lo, float hi) {
    unsigned r;
    asm("v_cvt_pk_bf16_f32 %0, %1, %2" : "=v"(r) : "v"(lo), "v"(hi));
    return r;
}
__device__ __forceinline__ float asf(unsigned u) {
    union { unsigned u; float f; } c; c.u = u; return c.f;
}

// ---------------------------------------------------------------------------
// Kernel 1: proj GEMM Y = X*W^T + b. VERIFIED math (R8/R9); regrouped as
// 384 blocks x 3 waves (was 1152 x 1 wave): same 1152 independent wave-tasks,
// ~4.5 waves/CU for load-latency hiding. No barriers; waves independent.
// task = blockIdx*3+wave: z = task/384; by = (task%384)/96; bx = task%96.
// ---------------------------------------------------------------------------
__global__ __launch_bounds__(192) void proj_kernel(
    const float* __restrict__ Xq, const float* __restrict__ Xk,
    const float* __restrict__ Xv,
    const float* __restrict__ Wq, const float* __restrict__ bq,
    const float* __restrict__ Wk, const float* __restrict__ bk,
    const float* __restrict__ Wv, const float* __restrict__ bv,
    ushort* __restrict__ qh, ushort* __restrict__ ql,
    ushort* __restrict__ kh, ushort* __restrict__ kl,
    ushort* __restrict__ vh, float* __restrict__ part)
{
    const int tid  = threadIdx.x;
    const int wave = tid >> 6;
    const int lane = tid & 63;
    const int task = blockIdx.x * 3 + wave;      // 0..1151
    const int z    = task / 384;
    const int rem  = task - z * 384;
    const int by   = rem / 96;
    const int bx   = rem - by * 96;

    const float* X    = (z == 0) ? Xq : (z == 1) ? Xk : Xv;
    const float* W    = (z == 0) ? Wq : (z == 1) ? Wk : Wv;
    const float* bias = (z == 0) ? bq : (z == 1) ? bk : bv;

    const int lg   = lane >> 4;
    const int ll   = lane & 15;
    const int row0 = bx * 16;
    const int col0 = by * 64;

    f32x4 acc[4];
    #pragma unroll
    for (int ct = 0; ct < 4; ++ct) acc[ct] = (f32x4){0.f, 0.f, 0.f, 0.f};

    for (int kk = 0; kk < 8; ++kk) {
        FragU ah, al;
        {
            const float* xp = &X[(size_t)(row0 + ll) * 256 + kk * 32 + lg * 8];
            const float4 x0 = *(const float4*)&xp[0];
            const float4 x1 = *(const float4*)&xp[4];
            const float xv[8] = {x0.x, x0.y, x0.z, x0.w, x1.x, x1.y, x1.z, x1.w};
            #pragma unroll
            for (int i = 0; i < 4; ++i) {
                const unsigned hd = cvt_pk(xv[2 * i], xv[2 * i + 1]);
                ah.d[i] = hd;
                al.d[i] = cvt_pk(xv[2 * i]     - asf(hd << 16),
                                 xv[2 * i + 1] - asf(hd & 0xffff0000u));
            }
        }
        #pragma unroll
        for (int ct = 0; ct < 4; ++ct) {
            const float* wp = &W[(size_t)(col0 + ct * 16 + ll) * 256 + kk * 32 + lg * 8];
            const float4 w0 = *(const float4*)&wp[0];
            const float4 w1 = *(const float4*)&wp[4];
            const float wv[8] = {w0.x, w0.y, w0.z, w0.w, w1.x, w1.y, w1.z, w1.w};
            FragU bh, bl;
            #pragma unroll
            for (int i = 0; i < 4; ++i) {
                const unsigned hd = cvt_pk(wv[2 * i], wv[2 * i + 1]);
                bh.d[i] = hd;
                bl.d[i] = cvt_pk(wv[2 * i]     - asf(hd << 16),
                                 wv[2 * i + 1] - asf(hd & 0xffff0000u));
            }
            acc[ct] = __builtin_amdgcn_mfma_f32_16x16x32_bf16(ah.v, bh.v, acc[ct], 0, 0, 0);
            acc[ct] = __builtin_amdgcn_mfma_f32_16x16x32_bf16(al.v, bh.v, acc[ct], 0, 0, 0);
            acc[ct] = __builtin_amdgcn_mfma_f32_16x16x32_bf16(ah.v, bl.v, acc[ct], 0, 0, 0);
        }
    }

    const int ae  = bx / 24;                     // a (q) or e (k,v)
    const int rbl = bx - ae * 24;
    float bct[4];
    #pragma unroll
    for (int ct = 0; ct < 4; ++ct) bct[ct] = bias[col0 + ct * 16 + ll];

    if (z != 2) {
        #pragma unroll
        for (int ct = 0; ct < 4; ++ct) {
            const int d = col0 + ct * 16 + ll;
            const int hd = d >> 5;
            const int c = d & 31;
            #pragma unroll
            for (int j = 0; j < 4; ++j) {
                const int n = rbl * 16 + lg * 4 + j;
                const float v = acc[ct][j] + bct[ct];
                const ushort hb = f2bf(v);
                const ushort lb = f2bf(v - bf2f(hb));
                if (z == 0) {
                    const size_t idx = ((size_t)((ae * 8 + hd) * 384 + n)) * 32 + c;
                    qh[idx] = hb; ql[idx] = lb;
                } else {
                    const size_t idx =
                        ((size_t)(((ae * 8 + hd) * 4 + (c >> 3)) * 384 + n)) * 8 + (c & 7);
                    kh[idx] = hb; kl[idx] = lb;
                }
            }
        }
        // exact fp32 column sums over this wave's 16 rows (incl. bias)
        #pragma unroll
        for (int ct = 0; ct < 4; ++ct) {
            float cs = 4.f * bct[ct];
            #pragma unroll
            for (int j = 0; j < 4; ++j) cs += acc[ct][j];
            cs += __shfl_xor(cs, 16);
            cs += __shfl_xor(cs, 32);
            if (lg == 0)
                part[((size_t)(z * 4 + ae) * 24 + rbl) * 256 + col0 + ct * 16 + ll] = cs;
        }
    } else {
        #pragma unroll
        for (int ct = 0; ct < 4; ++ct) {
            const int d = col0 + ct * 16 + ll;
            const int hd = d >> 5;
            const int c = d & 31;
            ushort p[4];
            #pragma unroll
            for (int j = 0; j < 4; ++j) p[j] = f2bf(acc[ct][j] + bct[ct]);
            const int m0 = rbl * 16 + lg * 4;
            const size_t basei = ((size_t)((ae * 8 + hd) * 32 + c)) * 384 + m0;
            *(uint2*)&vh[basei] =
                make_uint2((unsigned)p[0] | ((unsigned)p[1] << 16),
                           (unsigned)p[2] | ((unsigned)p[3] << 16));
        }
    }
}

// ---------------------------------------------------------------------------
// Kernel 2: stats. VERIFIED (R9). 1 block x 256 threads -> w[16].
// ---------------------------------------------------------------------------
__global__ __launch_bounds__(256) void stats_kernel(
    const float* __restrict__ part, float* __restrict__ wout)
{
    __shared__ float ws4[4][16];
    __shared__ float cellsh[16];
    const int tid = threadIdx.x;
    const int lane = tid & 63;
    const int wv = tid >> 6;

    float qs[4], ks[4];
    #pragma unroll
    for (int a2 = 0; a2 < 4; ++a2) {
        const float* pq = &part[(size_t)(0 * 4 + a2) * 24 * 256 + tid];
        const float* pk = &part[(size_t)(1 * 4 + a2) * 24 * 256 + tid];
        float sq = 0.f, sk = 0.f;
        #pragma unroll
        for (int r = 0; r < 24; ++r) {
            sq += pq[r * 256];
            sk += pk[r * 256];
        }
        qs[a2] = sq; ks[a2] = sk;
    }
    #pragma unroll
    for (int i = 0; i < 16; ++i) {
        float v = qs[i >> 2] * ks[i & 3];
        v += __shfl_xor(v, 1);
        v += __shfl_xor(v, 2);
        v += __shfl_xor(v, 4);
        v += __shfl_xor(v, 8);
        v += __shfl_xor(v, 16);
        v += __shfl_xor(v, 32);
        if (lane == 0) ws4[wv][i] = v;
    }
    __syncthreads();
    if (tid < 16)
        cellsh[tid] = 0.17677669529663687f *
            (ws4[0][tid] + ws4[1][tid] + ws4[2][tid] + ws4[3][tid]);
    __syncthreads();
    if (tid == 0) {
        const int TR[12][4] = {
            {0,1,2,3},{0,2,3,1},{0,3,1,2},{1,2,0,3},{1,0,3,2},{1,3,2,0},
            {2,3,0,1},{2,0,1,3},{2,1,3,0},{3,1,0,2},{3,0,2,1},{3,2,1,0}};
        const float denom = 4.0f * 8.0f * 384.0f * 384.0f;
        float pos[12];
        float psum = 0.f;
        for (int r = 0; r < 12; ++r) {
            float s = 0.f;
            for (int a2 = 0; a2 < 4; ++a2) s += cellsh[a2 * 4 + TR[r][a2]];
            const float pooled = s / denom;
            pos[r] = pooled * pooled;
            psum += pos[r];
        }
        float w[16];
        for (int i = 0; i < 16; ++i) w[i] = 0.f;
        const float ip = 1.f / psum;
        for (int r = 0; r < 12; ++r)
            for (int a2 = 0; a2 < 4; ++a2) w[a2 * 4 + TR[r][a2]] += pos[r] * ip;
        for (int i = 0; i < 16; ++i) wout[i] = w[i];
    }
}

// ---------------------------------------------------------------------------
// Kernel 3: MFMA flash attention per (a,e,h) x n-strip(96); R9 geometry
// (grid (4,128), 3 waves, 2 row-tiles/wave) with SWAPPED QK^T:
//   s = mfma(A=K, B=Q)  -> lane(lg,ll) reg j = score[k=M+lg*4+j][qrow=ll]
// so P is A-frag-shaped in registers (cvt_pk pack), eliminating the P LDS
// round trip. V is staged with a within-32-row permutation so its B-frag
// contraction order matches P's k order:
//   lds row M + g*8 + h*4 + r  <-  V row M + g*4 + r + 16*h
// L is reduced across lg (shfl_xor 16/32) + one __shfl transpose at write.
// ---------------------------------------------------------------------------
__global__ __launch_bounds__(192) void attn_mfma_kernel(
    const ushort* __restrict__ qhb, const ushort* __restrict__ qlb,
    const ushort* __restrict__ khb, const ushort* __restrict__ klb,
    const ushort* __restrict__ vhb, float* __restrict__ Sout)
{
    __shared__ ushort Kh[4 * 1544];      // [kblk][m:192][8] + 8-pad per kblk
    __shared__ ushort Kl[4 * 1544];
    __shared__ ushort Vh[32 * 200];      // [c][m:192 permuted] + pad

    const int strip = blockIdx.x;
    const int aeh   = blockIdx.y;          // a*32 + e*8 + h
    const int hh    = aeh & 7;
    const int ee    = (aeh >> 3) & 3;
    const int aa    = aeh >> 5;
    const int e8h   = ee * 8 + hh;
    const int a8h   = aa * 8 + hh;
    const int tid   = threadIdx.x;
    const int wave  = tid >> 6;
    const int lane  = tid & 63;
    const int lg    = lane >> 4;
    const int ll    = lane & 15;

    s8x8 qfh[2], qfl[2];
    #pragma unroll
    for (int r = 0; r < 2; ++r) {
        const int n0 = strip * 96 + (2 * wave + r) * 16;
        const size_t off = (size_t)(a8h * 384 + n0 + ll) * 32 + lg * 8;
        qfh[r] = *(const s8x8*)&qhb[off];
        qfl[r] = *(const s8x8*)&qlb[off];
    }

    f32x4 oacc[2][2];
    #pragma unroll
    for (int r = 0; r < 2; ++r)
        #pragma unroll
        for (int ct = 0; ct < 2; ++ct)
            oacc[r][ct] = (f32x4){0.f, 0.f, 0.f, 0.f};
    float lsum[2] = {0.f, 0.f};            // per-lane partial L for qrow=ll
    const float sc = 0.17677669529663687f; // 1/sqrt(32)

    for (int half = 0; half < 2; ++half) {
        #pragma unroll
        for (int i = 0; i < 4; ++i) {
            const size_t src = ((size_t)(e8h * 4 + i) * 384 + half * 192 + tid) * 8;
            *(uint4*)&Kh[i * 1544 + tid * 8] = *(const uint4*)&khb[src];
            *(uint4*)&Kl[i * 1544 + tid * 8] = *(const uint4*)&klb[src];
        }
        // V staging with within-32-chunk row permutation
        #pragma unroll
        for (int i = 0; i < 4; ++i) {
            const int u = tid + 192 * i;
            const int c = u / 24;
            const int t = u - c * 24;          // 0..23: 8 source rows each
            const int M = (t >> 2) * 32;       // 32-row chunk base
            const int q2 = t & 3;
            const int off = (q2 & 1) * 16 + (q2 >> 1) * 4;
            const uint4 src = *(const uint4*)
                &vhb[(size_t)(e8h * 32 + c) * 384 + half * 192 + t * 8];
            *(uint2*)&Vh[c * 200 + M + off]     = make_uint2(src.x, src.y);
            *(uint2*)&Vh[c * 200 + M + off + 8] = make_uint2(src.z, src.w);
        }
        __syncthreads();

        for (int mt2 = 0; mt2 < 6; ++mt2) {
            float pv_[2][8];
            #pragma unroll
            for (int sub = 0; sub < 2; ++sub) {
                const int mt = mt2 * 2 + sub;
                const s8x8 kfh = *(const s8x8*)&Kh[lg * 1544 + (mt * 16 + ll) * 8];
                const s8x8 kfl = *(const s8x8*)&Kl[lg * 1544 + (mt * 16 + ll) * 8];
                #pragma unroll
                for (int r = 0; r < 2; ++r) {
                    f32x4 s = {0.f, 0.f, 0.f, 0.f};
                    __builtin_amdgcn_s_setprio(1);
                    s = __builtin_amdgcn_mfma_f32_16x16x32_bf16(kfh, qfh[r], s, 0, 0, 0);
                    s = __builtin_amdgcn_mfma_f32_16x16x32_bf16(kfl, qfh[r], s, 0, 0, 0);
                    s = __builtin_amdgcn_mfma_f32_16x16x32_bf16(kfh, qfl[r], s, 0, 0, 0);
                    __builtin_amdgcn_s_setprio(0);
                    #pragma unroll
                    for (int j = 0; j < 4; ++j) {
                        const float p = __expf(s[j] * sc);
                        lsum[r] += p;
                        pv_[r][sub * 4 + j] = p;
                    }
                }
            }
            const int mloc = mt2 * 32;
            const s8x8 vf0 = *(const s8x8*)&Vh[(0  + ll) * 200 + mloc + lg * 8];
            const s8x8 vf1 = *(const s8x8*)&Vh[(16 + ll) * 200 + mloc + lg * 8];
            #pragma unroll
            for (int r = 0; r < 2; ++r) {
                FragU pu;
                pu.d[0] = cvt_pk(pv_[r][0], pv_[r][1]);
                pu.d[1] = cvt_pk(pv_[r][2], pv_[r][3]);
                pu.d[2] = cvt_pk(pv_[r][4], pv_[r][5]);
                pu.d[3] = cvt_pk(pv_[r][6], pv_[r][7]);
                __builtin_amdgcn_s_setprio(1);
                oacc[r][0] = __builtin_amdgcn_mfma_f32_16x16x32_bf16(pu.v, vf0, oacc[r][0], 0, 0, 0);
                oacc[r][1] = __builtin_amdgcn_mfma_f32_16x16x32_bf16(pu.v, vf1, oacc[r][1], 0, 0, 0);
                __builtin_amdgcn_s_setprio(0);
            }
        }
        __syncthreads();
    }

    // finalize: L per qrow lives at lane ll (all lg); transpose via __shfl
    #pragma unroll
    for (int r = 0; r < 2; ++r) {
        float L = lsum[r];
        L += __shfl_xor(L, 16);
        L += __shfl_xor(L, 32);
        #pragma unroll
        for (int j = 0; j < 4; ++j) {
            const float Lrow = __shfl(L, lg * 4 + j);
            const float invL = 1.f / Lrow;
            const int row = strip * 96 + (2 * wave + r) * 16 + lg * 4 + j;
            const size_t base = (size_t)(aeh * 384 + row) * 32;
            Sout[base + 0  + ll] = oacc[r][0][j] * invL;
            Sout[base + 16 + ll] = oacc[r][1][j] * invL;
        }
    }
}

// ---------------------------------------------------------------------------
// Kernel 4: combine. VERIFIED (R9). Reads w[16];
// out[a,n,h*32+c] = sum_e w[a,e]*S[(a,e),h,n,c]. grid 384 x 256.
// ---------------------------------------------------------------------------
__global__ __launch_bounds__(256) void combine_kernel(
    const float* __restrict__ S, const float* __restrict__ wbuf,
    float* __restrict__ out)
{
    __shared__ float wsh[16];
    const int tid = threadIdx.x;
    if (tid < 16) wsh[tid] = wbuf[tid];
    __syncthreads();

    const int idx4 = blockIdx.x * 256 + tid;   // 0..98303
    const int a = idx4 / 24576;
    const int rem = idx4 - a * 24576;
    const int n = rem >> 6;
    const int d4 = rem & 63;
    const int h = d4 >> 3;
    const int c0 = (d4 & 7) * 4;
    float4 r = make_float4(0.f, 0.f, 0.f, 0.f);
    #pragma unroll
    for (int e = 0; e < 4; ++e) {
        const float wv2 = wsh[a * 4 + e];
        const float4 s = *(const float4*)&S[(size_t)(((a * 4 + e) * 8 + h) * 384 + n) * 32 + c0];
        r.x += wv2 * s.x; r.y += wv2 * s.y; r.z += wv2 * s.z; r.w += wv2 * s.w;
    }
    *(float4*)&out[(size_t)idx4 * 4] = r;
}

// ---------------------------------------------------------------------------
extern "C" void kernel_launch(void* const* d_in, const int* in_sizes, int n_in,
                              void* d_out, int out_size, void* d_ws, size_t ws_size,
                              hipStream_t stream)
{
    const float* in_q = (const float*)d_in[0];
    const float* in_k = (const float*)d_in[1];
    const float* in_v = (const float*)d_in[2];
    const float* Wq   = (const float*)d_in[3];
    const float* bq   = (const float*)d_in[4];
    const float* Wk   = (const float*)d_in[5];
    const float* bk   = (const float*)d_in[6];
    const float* Wv   = (const float*)d_in[7];
    const float* bv   = (const float*)d_in[8];

    ushort* qh = (ushort*)d_ws;               // 393216
    ushort* ql = qh + 393216;                 // 393216
    ushort* kh = ql + 393216;                 // 393216
    ushort* kl = kh + 393216;                 // 393216
    ushort* vh = kl + 393216;                 // 393216
    float*  Sb = (float*)(vh + 393216);       // 1572864 floats
    float*  pt = Sb + 1572864;                // 49152 floats (column sums)
    float*  wb = pt + 49152;                  // 16 weights
    float*  outp = (float*)d_out;

    proj_kernel<<<384, 192, 0, stream>>>(in_q, in_k, in_v, Wq, bq, Wk, bk,
                                         Wv, bv, qh, ql, kh, kl, vh, pt);
    stats_kernel<<<1, 256, 0, stream>>>(pt, wb);
    dim3 agrid(4, 128);
    attn_mfma_kernel<<<agrid, 192, 0, stream>>>(qh, ql, kh, kl, vh, Sb);
    combine_kernel<<<384, 256, 0, stream>>>(Sb, wb, outp);
}